// Round 8
// baseline (346.553 us; speedup 1.0000x reference)
//
#include <hip/hip_runtime.h>
#include <hip/hip_bf16.h>

// GQA block: B=2, S=2048, HID=2048, H=32, G=8, D=64, QPG=4.
// bf16 MFMA 16x16x32; fp32 accumulate. m97-style staging primitives:
// global_load_lds width=16 into unpadded LDS with XOR swizzle
// (chunk_phys = chunk_log ^ (row&7); rows of 64 shorts = 8 chunks of 16B).
// Fragment layouts (HW-verified, learn_hip m89/m120):
//   A-frag:  A[m=lane&15][k=quad*8+j]
//   B-frag:  B[k=quad*8+j][n=lane&15]
//   C/D:     col(n)=lane&15, row(m)=quad*4+reg
// Attention: S^T = K Q^T, O^T = V^T P^T; no-max softmax; in-register P
// butterfly (R10: cvt_pk_bf16 + permlane swaps; attn 80.5 us, conflicts 0).
// R14 instrumentation: QKV GEMM = 86 us @ MfmaUtil 24% (m97 128^2 structure at
// its shape-curve level); out-proj ~78; GEMMs = 165 us > attn. 1-D XCD swizzle
// + attn split were net regression -> reverted.
// R15: both GEMMs -> 256^2 4-phase/tile counted-vmcnt schedule (T3+T4+T5):
//   8 waves (2Mx4N), per-wave C = 128x64 (acc 8x4), BK=64, LDS 128 KB dbuf.
//   Slabs: A-quarters (64 rows, 1 instr/wave) + B-halves (128 rows, 2/wave).
//   Tile t's block issues tile t+1 into buf^1: ph1:Bh0 ph2:Bh1 ph3:Aq0,q2
//   ph4:Aq1,q3. vmcnt(4) before ph3 (drains t's hi quarters), vmcnt(2) at
//   tile boundary (drains next tile's ph1 needs, keeps its hi quarters in
//   flight). Raw s_barrier (no implicit drain), never vmcnt(0) in-loop.

typedef __attribute__((ext_vector_type(8))) short shortx8;
typedef __attribute__((ext_vector_type(4))) float floatx4;

#define SEQ 2048
#define QSC 0.1803368801111204f   // (1/8) * log2(e), folded into Wq/bq

#if __has_builtin(__builtin_amdgcn_exp2f)
#define EXP2F(x) __builtin_amdgcn_exp2f(x)
#else
#define EXP2F(x) __expf((x) * 0.6931471805599453f)
#endif

__device__ __forceinline__ unsigned short f2bf(float f) {      // RNE
  union { float f; unsigned u; } a; a.f = f;
  unsigned u = a.u;
  u += 0x7fffu + ((u >> 16) & 1u);
  return (unsigned short)(u >> 16);
}

// packed f32x2 -> bf16x2 (RNE), single instruction
__device__ __forceinline__ unsigned cvtpkbf(float lo, float hi) {
  unsigned r;
  asm("v_cvt_pk_bf16_f32 %0, %1, %2" : "=v"(r) : "v"(lo), "v"(hi));
  return r;
}

// v_permlane32_swap_b32: a = {a_lo32, b_lo32}, b = {a_hi32, b_hi32}
// s_nop guard: permlane cross-lane reads need producer wait states; the
// compiler's hazard recognizer can't see inside inline asm, so guard here.
__device__ __forceinline__ void plswap(unsigned &a, unsigned &b) {
  asm("s_nop 1\n\tv_permlane32_swap_b32 %0, %1" : "+v"(a), "+v"(b));
}
// v_permlane16_swap_b32: within each 32-half, a = {a_lo16, b_lo16}, b = {a_hi16, b_hi16}
__device__ __forceinline__ void pl16swap(unsigned &a, unsigned &b) {
  asm("s_nop 1\n\tv_permlane16_swap_b32 %0, %1" : "+v"(a), "+v"(b));
}

// async global->LDS, 16B per lane; LDS dst = uniform base + lane*16
__device__ __forceinline__ void gload16(const unsigned short* g, unsigned short* l) {
  __builtin_amdgcn_global_load_lds((const __attribute__((address_space(1))) void*)g,
                                   (__attribute__((address_space(3))) void*)l, 16, 0, 0);
}

// ---------------- prep v2: flat 1-D grid, no idle blocks ----------------
// blocks 0..2559: 64x64 weight-transpose tiles (Wq 1024 | Wk 256 | Wv 256 | Wo 1024)
// blocks 2560..3583: x cast (8192 elems each)
// block 3584: bias concat
__global__ __launch_bounds__(256) void prep_kernel(const float* __restrict__ x,
                            const float* __restrict__ Wq, const float* __restrict__ Wk,
                            const float* __restrict__ Wv, const float* __restrict__ Wo,
                            const float* __restrict__ bq, const float* __restrict__ bk,
                            const float* __restrict__ bv,
                            unsigned short* __restrict__ WT,
                            unsigned short* __restrict__ WoT,
                            unsigned short* __restrict__ xb,
                            float* __restrict__ bqkv) {
  const int bid = blockIdx.x, tid = threadIdx.x;
  if (bid < 2560) {                   // weight transpose: 64x64 tile per block
    const float* W; unsigned short* D; int N, ox, oy; float sc = 1.f;
    if (bid < 1024)      { W = Wq; D = WT;               N = 2048; ox = bid & 31;          oy = bid >> 5;          sc = QSC; }
    else if (bid < 1280) { W = Wk; D = WT + 2048 * 2048; N = 512;  ox = (bid - 1024) & 7;  oy = (bid - 1024) >> 3; }
    else if (bid < 1536) { W = Wv; D = WT + 2560 * 2048; N = 512;  ox = (bid - 1280) & 7;  oy = (bid - 1280) >> 3; }
    else                 { W = Wo; D = WoT;              N = 2048; ox = (bid - 1536) & 31; oy = (bid - 1536) >> 5; }
    __shared__ float tile[64][65];
    const int tx = tid & 63, ty = tid >> 6;
    const int r0 = oy * 64, c0 = ox * 64;   // r = input index, c = output index
#pragma unroll
    for (int i = 0; i < 64; i += 4)
      tile[ty + i][tx] = W[(size_t)(r0 + ty + i) * N + c0 + tx];
    __syncthreads();
    // D[out][in] = W[in][out] * sc; writes coalesced over tx (in-dim)
#pragma unroll
    for (int i = 0; i < 64; i += 4)
      D[(size_t)(c0 + ty + i) * 2048 + r0 + tx] = f2bf(tile[tx][ty + i] * sc);
    return;
  }
  if (bid < 3584) {                   // cast x -> bf16, 8192 floats per block
    const size_t base = (size_t)(bid - 2560) * 8192;
#pragma unroll
    for (int k = 0; k < 4; k++) {
      size_t i = base + (size_t)k * 2048 + tid * 8;
      float4 v0 = *(const float4*)(x + i);
      float4 v1 = *(const float4*)(x + i + 4);
      ushort4 o0, o1;
      o0.x = f2bf(v0.x); o0.y = f2bf(v0.y); o0.z = f2bf(v0.z); o0.w = f2bf(v0.w);
      o1.x = f2bf(v1.x); o1.y = f2bf(v1.y); o1.z = f2bf(v1.z); o1.w = f2bf(v1.w);
      *(ushort4*)(xb + i) = o0;
      *(ushort4*)(xb + i + 4) = o1;
    }
    return;
  }
  // bias concat
  for (int i = tid; i < 3072; i += 256)
    bqkv[i] = i < 2048 ? bq[i] * QSC : (i < 2560 ? bk[i - 2048] : bv[i - 2560]);
}

// ---------------- 256x256 bf16 GEMM, 4-phase counted-vmcnt ----------------
// C = A @ BT^T + bias. 512 threads = 8 waves (wm = wave>>2 in {0,1}, wn = wave&3).
// Per-wave C: rows m0+wm*128+mi*16 (mi 0..7), cols n0+wn*64+nj*16 (nj 0..3).
// MODE 0: fp32 out. MODE 2: QKV split (Q bf16, K -> Kbuf, V -> Vt[gb][d][s]).
template <int MODE>
__global__ __launch_bounds__(512, 1) void gemm256(const unsigned short* __restrict__ A,
                                                  const unsigned short* __restrict__ BT,
                                                  const float* __restrict__ bias,
                                                  void* __restrict__ Cout,
                                                  unsigned short* __restrict__ Kbuf,
                                                  unsigned short* __restrict__ Vt,
                                                  int M, int N, int K) {
  __shared__ __align__(16) unsigned short As[2][256 * 64];   // 64 KB
  __shared__ __align__(16) unsigned short Bs[2][256 * 64];   // 64 KB
  const int tid = threadIdx.x, lane = tid & 63, wave = tid >> 6;
  const int wm = wave >> 2, wn = wave & 3;
  const int l15 = lane & 15, quad = lane >> 4;
  const int m0 = blockIdx.x * 256, n0 = blockIdx.y * 256;

  // staging sources: each gload16 covers 8 rows (lane>>3) x 64 shorts, swizzled
  const int r8 = lane >> 3;
  const int clog = (lane & 7) ^ r8;
  const unsigned short* aS = A + (size_t)(m0 + wave * 8 + r8) * K + clog * 8;
  const unsigned short* bS = BT + (size_t)(n0 + wave * 16 + r8) * K + clog * 8;

  // A slab q (rows q*64..+63): wave stages rows q*64 + wave*8 + 0..7 (1 instr)
  // B half h (rows h*128..+127): wave stages rows h*128 + wave*16 + j*8 + 0..7 (2 instr)
#define ISS_A(buf, q, kc) gload16(aS + (size_t)(q) * 64 * K + (kc), &As[buf][(q) * 4096 + wave * 512])
#define ISS_B(buf, h, j, kc) gload16(bS + (size_t)((h) * 128 + (j) * 8) * K + (kc), &Bs[buf][(h) * 8192 + wave * 1024 + (j) * 512])

  const int s = l15 & 7;
  int aoff[8], boff[4];
#pragma unroll
  for (int mi = 0; mi < 8; mi++) aoff[mi] = (wm * 128 + mi * 16 + l15) * 64 + (quad ^ s) * 8;
#pragma unroll
  for (int nj = 0; nj < 4; nj++) boff[nj] = (wn * 64 + nj * 16 + l15) * 64 + (quad ^ s) * 8;

  floatx4 acc[8][4];
#pragma unroll
  for (int i = 0; i < 8; i++)
#pragma unroll
    for (int j = 0; j < 4; j++)
#pragma unroll
      for (int r = 0; r < 4; r++) acc[i][j][r] = 0.f;

  // prologue: stage tile 0 into buf 0, full drain (allowed outside main loop)
  ISS_A(0, 0, 0); ISS_A(0, 1, 0); ISS_A(0, 2, 0); ISS_A(0, 3, 0);
  ISS_B(0, 0, 0, 0); ISS_B(0, 0, 1, 0); ISS_B(0, 1, 0, 0); ISS_B(0, 1, 1, 0);
  asm volatile("s_waitcnt vmcnt(0)" ::: "memory");
  __builtin_amdgcn_s_barrier();
  asm volatile("" ::: "memory");

  const int NT = K >> 6;
  for (int t = 0; t < NT; ++t) {
    const int b = t & 1;
    const bool pf = (t + 1 < NT);
    const int kc1 = (t + 1) << 6;
    shortx8 af[4], bf0[4], bf1[4];

    // ---- phase 1: (mi 0-3) x (nj 0-3) x ks0 ----
#pragma unroll
    for (int i = 0; i < 4; i++) af[i] = *(const shortx8*)&As[b][aoff[i]];
#pragma unroll
    for (int j = 0; j < 4; j++) bf0[j] = *(const shortx8*)&Bs[b][boff[j]];
    if (pf) { ISS_B(b ^ 1, 0, 0, kc1); ISS_B(b ^ 1, 0, 1, kc1); }
    __builtin_amdgcn_s_barrier();
    asm volatile("" ::: "memory");
    __builtin_amdgcn_s_setprio(1);
#pragma unroll
    for (int i = 0; i < 4; i++)
#pragma unroll
      for (int j = 0; j < 4; j++)
        acc[i][j] = __builtin_amdgcn_mfma_f32_16x16x32_bf16(af[i], bf0[j], acc[i][j], 0, 0, 0);
    __builtin_amdgcn_s_setprio(0);
    __builtin_amdgcn_s_barrier();
    asm volatile("" ::: "memory");

    // ---- phase 2: (mi 0-3) x (nj 0-3) x ks1 ----
#pragma unroll
    for (int i = 0; i < 4; i++) af[i] = *(const shortx8*)&As[b][aoff[i] ^ 32];
#pragma unroll
    for (int j = 0; j < 4; j++) bf1[j] = *(const shortx8*)&Bs[b][boff[j] ^ 32];
    if (pf) { ISS_B(b ^ 1, 1, 0, kc1); ISS_B(b ^ 1, 1, 1, kc1); }
    __builtin_amdgcn_s_barrier();
    asm volatile("" ::: "memory");
    __builtin_amdgcn_s_setprio(1);
#pragma unroll
    for (int i = 0; i < 4; i++)
#pragma unroll
      for (int j = 0; j < 4; j++)
        acc[i][j] = __builtin_amdgcn_mfma_f32_16x16x32_bf16(af[i], bf1[j], acc[i][j], 0, 0, 0);
    __builtin_amdgcn_s_setprio(0);
    // drain tile t's hi A-quarters (issued prev block ph4) before ph3 reads them;
    // keep tile t+1's Bh0/Bh1 (4 instr) in flight.
    if (pf) { asm volatile("s_waitcnt vmcnt(4)" ::: "memory"); }
    else    { asm volatile("s_waitcnt vmcnt(0)" ::: "memory"); }
    __builtin_amdgcn_s_barrier();
    asm volatile("" ::: "memory");

    // ---- phase 3: (mi 4-7) x (nj 0-3) x ks0 ----
#pragma unroll
    for (int i = 0; i < 4; i++) af[i] = *(const shortx8*)&As[b][aoff[4 + i]];
    if (pf) { ISS_A(b ^ 1, 0, kc1); ISS_A(b ^ 1, 2, kc1); }
    __builtin_amdgcn_s_barrier();
    asm volatile("" ::: "memory");
    __builtin_amdgcn_s_setprio(1);
#pragma unroll
    for (int i = 0; i < 4; i++)
#pragma unroll
      for (int j = 0; j < 4; j++)
        acc[4 + i][j] = __builtin_amdgcn_mfma_f32_16x16x32_bf16(af[i], bf0[j], acc[4 + i][j], 0, 0, 0);
    __builtin_amdgcn_s_setprio(0);
    __builtin_amdgcn_s_barrier();
    asm volatile("" ::: "memory");

    // ---- phase 4: (mi 4-7) x (nj 0-3) x ks1 ----
#pragma unroll
    for (int i = 0; i < 4; i++) af[i] = *(const shortx8*)&As[b][aoff[4 + i] ^ 32];
    if (pf) { ISS_A(b ^ 1, 1, kc1); ISS_A(b ^ 1, 3, kc1); }
    __builtin_amdgcn_s_barrier();
    asm volatile("" ::: "memory");
    __builtin_amdgcn_s_setprio(1);
#pragma unroll
    for (int i = 0; i < 4; i++)
#pragma unroll
      for (int j = 0; j < 4; j++)
        acc[4 + i][j] = __builtin_amdgcn_mfma_f32_16x16x32_bf16(af[i], bf1[j], acc[4 + i][j], 0, 0, 0);
    __builtin_amdgcn_s_setprio(0);
    // tile boundary: drain tile t+1's ph1 needs (Bh0,Bh1,Aq0,Aq2), keep its
    // Aq1,Aq3 (2 instr, needed only at its ph3) in flight. Never 0 mid-loop.
    if (pf) { asm volatile("s_waitcnt vmcnt(2)" ::: "memory"); }
    __builtin_amdgcn_s_barrier();
    asm volatile("" ::: "memory");
  }

  // epilogue
#pragma unroll
  for (int mi = 0; mi < 8; mi++) {
#pragma unroll
    for (int nj = 0; nj < 4; nj++) {
      int col = n0 + wn * 64 + nj * 16 + l15;
      float bv = bias[col];
#pragma unroll
      for (int r = 0; r < 4; r++) {
        int row = m0 + wm * 128 + mi * 16 + quad * 4 + r;
        float v = acc[mi][nj][r] + bv;
        if (MODE == 0) {
          ((float*)Cout)[(size_t)row * N + col] = v;
        } else {
          if (col < 2048) {
            ((unsigned short*)Cout)[(size_t)row * 2048 + col] = f2bf(v);
          } else if (col < 2560) {
            Kbuf[(size_t)row * 512 + (col - 2048)] = f2bf(v);
          } else {
            int g = (col - 2560) >> 6, d = (col - 2560) & 63;
            int bb = row >> 11, sidx = row & 2047;
            Vt[(size_t)(((g << 1) | bb) * 64 + d) * 2048 + sidx] = f2bf(v);
          }
        }
      }
    }
  }
#undef ISS_A
#undef ISS_B
}

// ---------------- flash attention (group-shared K/V, dbuf, in-register P) --------
// grid (S/32=64, G=8, B=2); wave w = head g*4+w. Each wave: 32 q rows as 2
// q-sets of 16. K/V dbuf (1 barrier/tile). P stays in registers: QK C-frag is
// redistributed to PV B-frag via permlane32_swap then permlane16_swap (pure
// VALU butterfly, zero selects / LDS ops). LDS 32 KB -> 5 blocks/CU cap.
__global__ __launch_bounds__(256, 4) void attn_kernel(const unsigned short* __restrict__ Qb,
                                                      const unsigned short* __restrict__ Kb,
                                                      const unsigned short* __restrict__ Vt,
                                                      unsigned short* __restrict__ O) {
  const int qt = blockIdx.x, g = blockIdx.y, b = blockIdx.z;
  const int tid = threadIdx.x;
  const int lane = tid & 63, wave = tid >> 6;
  const int h = g * 4 + wave;
  const int l15 = lane & 15, quad = lane >> 4;

  __shared__ __align__(16) unsigned short Ks[2][64 * 64];  // [t][d] swizzled, 2x8 KB
  __shared__ __align__(16) unsigned short Vs[2][64 * 64];  // [d][t] swizzled, 2x8 KB

  // Q fragments for 2 q-sets (32 q rows per wave)
  shortx8 qf[2][2];
  {
    const unsigned short* qp = Qb + (size_t)(b * SEQ + qt * 32 + l15) * 2048 + h * 64 + quad * 8;
#pragma unroll
    for (int a = 0; a < 2; a++) {
      qf[a][0] = *(const shortx8*)(qp + (size_t)a * 16 * 2048);
      qf[a][1] = *(const shortx8*)(qp + (size_t)a * 16 * 2048 + 32);
    }
  }

  // staging: wave stages rows wave*16..+15 of each tile (2 issues of 8 rows)
  const int r8 = lane >> 3;
  const int clog = (lane & 7) ^ r8;
  const unsigned short* kSrc = Kb + ((size_t)b * SEQ + wave * 16 + r8) * 512 + g * 64 + clog * 8;
  const unsigned short* vSrc = Vt + ((size_t)((g * 2 + b) * 64 + wave * 16 + r8)) * 2048 + clog * 8;

  const int s = l15 & 7;
  int foff[4];
#pragma unroll
  for (int i = 0; i < 4; i++) foff[i] = (i * 16 + l15) * 64 + ((quad ^ s) * 8);

  shortx8 ones;
#pragma unroll
  for (int j = 0; j < 8; j++) ones[j] = (short)0x3F80;     // bf16 1.0

  floatx4 oacc[2][4], lacc[2];
#pragma unroll
  for (int a = 0; a < 2; a++) {
#pragma unroll
    for (int r = 0; r < 4; r++) lacc[a][r] = 0.f;
#pragma unroll
    for (int nd = 0; nd < 4; nd++)
#pragma unroll
      for (int r = 0; r < 4; r++) oacc[a][nd][r] = 0.f;
  }

  // prologue: stage tile 0 into buffer 0
  {
    unsigned short* kD = &Ks[0][wave * 1024];
    unsigned short* vD = &Vs[0][wave * 1024];
    gload16(kSrc, kD);
    gload16(kSrc + (size_t)8 * 512, kD + 512);
    gload16(vSrc, vD);
    gload16(vSrc + (size_t)8 * 2048, vD + 512);
  }
  __syncthreads();

  for (int it = 0; it < SEQ / 64; it++) {
    const int p = it & 1;
    // prefetch next tile into the other buffer (async; drained by the
    // end-of-iter barrier, ~1 tile of compute later)
    if (it < SEQ / 64 - 1) {
      const size_t t1 = (size_t)(it + 1) * 64;
      unsigned short* kD = &Ks[p ^ 1][wave * 1024];
      unsigned short* vD = &Vs[p ^ 1][wave * 1024];
      gload16(kSrc + t1 * 512, kD);
      gload16(kSrc + (t1 + 8) * 512, kD + 512);
      gload16(vSrc + t1, vD);
      gload16(vSrc + (size_t)8 * 2048 + t1, vD + 512);
    }

    // K fragments (reused by both q-sets)
    shortx8 kf[4][2];
#pragma unroll
    for (int i = 0; i < 4; i++) {
      kf[i][0] = *(const shortx8*)&Ks[p][foff[i]];
      kf[i][1] = *(const shortx8*)&Ks[p][foff[i] ^ 32];
    }

    // phase 1: per q-set QK^T -> exp -> pure-VALU butterfly -> PV B-frags.
    // sc[i][r] = score[t = i*16 + quad*4 + r][q = l15]. Pack pairs (cvt_pk):
    // E[i][c] = pair(t = 16i + 4quad + 2c). Target: pfr[a][ks].u32[m] =
    // pair(t = 32ks + 8quad + 2m): element W[i][c]@(b4,b5) lands at
    // lane(b4'=b5, b5'=i&1), slot m=2*b4+c, ks=i>>1 via plswap then pl16swap.
    shortx8 pfr[2][2];
#pragma unroll
    for (int a = 0; a < 2; a++) {
      floatx4 sc[4];
      __builtin_amdgcn_s_setprio(1);
#pragma unroll
      for (int i = 0; i < 4; i++) {
        floatx4 c = {0.f, 0.f, 0.f, 0.f};
        c = __builtin_amdgcn_mfma_f32_16x16x32_bf16(kf[i][0], qf[a][0], c, 0, 0, 0);
        c = __builtin_amdgcn_mfma_f32_16x16x32_bf16(kf[i][1], qf[a][1], c, 0, 0, 0);
        sc[i] = c;
      }
      __builtin_amdgcn_s_setprio(0);
      unsigned E00 = cvtpkbf(EXP2F(sc[0][0]), EXP2F(sc[0][1]));
      unsigned E01 = cvtpkbf(EXP2F(sc[0][2]), EXP2F(sc[0][3]));
      unsigned E10 = cvtpkbf(EXP2F(sc[1][0]), EXP2F(sc[1][1]));
      unsigned E11 = cvtpkbf(EXP2F(sc[1][2]), EXP2F(sc[1][3]));
      unsigned E20 = cvtpkbf(EXP2F(sc[2][0]), EXP2F(sc[2][1]));
      unsigned E21 = cvtpkbf(EXP2F(sc[2][2]), EXP2F(sc[2][3]));
      unsigned E30 = cvtpkbf(EXP2F(sc[3][0]), EXP2F(sc[3][1]));
      unsigned E31 = cvtpkbf(EXP2F(sc[3][2]), EXP2F(sc[3][3]));
      // stage A: lane^32 routing (b5' = i&1)
      plswap(E00, E10); plswap(E01, E11);   // ks=0
      plswap(E20, E30); plswap(E21, E31);   // ks=1
      // stage B: lane^16 routing (src b4 = m>>1) — no selects needed
      pl16swap(E00, E10); pl16swap(E01, E11);
      pl16swap(E20, E30); pl16swap(E21, E31);
      union { unsigned u[4]; shortx8 v; } P0, P1;
      P0.u[0] = E00; P0.u[1] = E01; P0.u[2] = E10; P0.u[3] = E11;
      P1.u[0] = E20; P1.u[1] = E21; P1.u[2] = E30; P1.u[3] = E31;
      pfr[a][0] = P0.v;
      pfr[a][1] = P1.v;
    }

    // phase 2: V fragments, then PV + l row-sum for both q-sets (MFMA burst)
    shortx8 vf[4][2];
#pragma unroll
    for (int nd = 0; nd < 4; nd++) {
      vf[nd][0] = *(const shortx8*)&Vs[p][foff[nd]];
      vf[nd][1] = *(const shortx8*)&Vs[p][foff[nd] ^ 32];
    }
#pragma unroll
    for (int a = 0; a < 2; a++) {
#pragma unroll
      for (int ks = 0; ks < 2; ks++) {
        shortx8 pf = pfr[a][ks];
        __builtin_amdgcn_s_setprio(1);
#pragma unroll
        for (int nd = 0; nd < 4; nd++)
          oacc[a][nd] = __builtin_amdgcn_mfma_f32_16x16x32_bf16(vf[nd][ks], pf, oacc[a][nd], 0, 0, 0);
        lacc[a] = __builtin_amdgcn_mfma_f32_16x16x32_bf16(ones, pf, lacc[a], 0, 0, 0);
        __builtin_amdgcn_s_setprio(0);
      }
    }
    __syncthreads();   // buffer p free; prefetch into p^1 drained
  }

  // epilogue: lacc rows identical -> l = lacc[a][0]; O^T cols q, rows d contiguous
#pragma unroll
  for (int a = 0; a < 2; a++) {
    float inv = 1.f / lacc[a][0];
    unsigned short* oPtr = O + (size_t)(b * SEQ + qt * 32 + a * 16 + l15) * 2048 + h * 64 + quad * 4;
#pragma unroll
    for (int nd = 0; nd < 4; nd++) {
      uint2 w;
      w.x = (unsigned)f2bf(oacc[a][nd][0] * inv) | ((unsigned)f2bf(oacc[a][nd][1] * inv) << 16);
      w.y = (unsigned)f2bf(oacc[a][nd][2] * inv) | ((unsigned)f2bf(oacc[a][nd][3] * inv) << 16);
      *(uint2*)(oPtr + nd * 16) = w;
    }
  }
}

extern "C" void kernel_launch(void* const* d_in, const int* in_sizes, int n_in,
                              void* d_out, int out_size, void* d_ws, size_t ws_size,
                              hipStream_t stream) {
  const float* x  = (const float*)d_in[0];
  const float* Wq = (const float*)d_in[1];
  const float* bq = (const float*)d_in[2];
  const float* Wk = (const float*)d_in[3];
  const float* bk = (const float*)d_in[4];
  const float* Wv = (const float*)d_in[5];
  const float* bv = (const float*)d_in[6];
  const float* Wo = (const float*)d_in[7];
  const float* bo = (const float*)d_in[8];
  float* out = (float*)d_out;

  // workspace layout (62,930,944 B total)
  char* ws = (char*)d_ws;
  unsigned short* WTall = (unsigned short*)ws;                          // [3072][2048] 12,582,912
  unsigned short* WoT   = (unsigned short*)(ws + 12582912);             // [2048][2048]  8,388,608
  float*          bqkv  = (float*)(ws + 20971520);                      // [3072] + pad      16384
  unsigned short* xb    = (unsigned short*)(ws + 20987904);             // [4096][2048] 16,777,216
  unsigned short* Qbuf  = (unsigned short*)(ws + 37765120);             // [4096][2048] 16,777,216
  unsigned short* Kbuf  = (unsigned short*)(ws + 54542336);             // [4096][512]   4,194,304
  unsigned short* Vt    = (unsigned short*)(ws + 58736640);             // [16][64][2048] 4,194,304
  unsigned short* Og    = xb;  // attention output reuses xb

  // 1. prep: cast x, transpose+cast weights (Wq pre-scaled), concat bias
  prep_kernel<<<dim3(3585), dim3(256), 0, stream>>>(
      x, Wq, Wk, Wv, Wo, bq, bk, bv, WTall, WoT, xb, bqkv);

  // 2. QKV projection: Q -> Qbuf, K -> Kbuf, V -> Vt (transposed)
  gemm256<2><<<dim3(16, 12), 512, 0, stream>>>(xb, WTall, bqkv, Qbuf, Kbuf, Vt, 4096, 3072, 2048);

  // 3. grouped flash attention -> Og [4096][2048] bf16
  attn_kernel<<<dim3(64, 8, 2), 256, 0, stream>>>(Qbuf, Kbuf, Vt, Og);

  // 4. output projection -> fp32 out
  gemm256<0><<<dim3(16, 8), 512, 0, stream>>>(Og, WoT, bo, out, nullptr, nullptr, 4096, 2048, 2048);
}

// Round 9
// 304.701 us; speedup vs baseline: 1.1374x; 1.1374x over previous
//
#include <hip/hip_runtime.h>
#include <hip/hip_bf16.h>

// GQA block: B=2, S=2048, HID=2048, H=32, G=8, D=64, QPG=4.
// bf16 MFMA 16x16x32; fp32 accumulate. m97-style staging:
// global_load_lds width=16 into unpadded LDS with XOR swizzle
// (chunk_phys = chunk_log ^ (row&7); rows of 64 shorts = 8 chunks of 16B).
// Fragment layouts (HW-verified, learn_hip m89/m120):
//   A-frag:  A[m=lane&15][k=quad*8+j]
//   B-frag:  B[k=quad*8+j][n=lane&15]
//   C/D:     col(n)=lane&15, row(m)=quad*4+reg
// Attention: S^T = K Q^T, O^T = V^T P^T (softmax axis on regs+quads).
// No-max softmax (scores ~N(0,0.9), exp2 has 2^30 headroom, shift-invariant).
// R10: in-register P butterfly (cvt_pk_bf16 + permlane swaps); attn 80.5 us,
//      conflicts 0, VGPR 64. BEST attn structure (32q/wave, 4 blk/CU).
// R12: 64q closed (TLP > amortization). R14: 1-D XCD swizzle hurt gemm
//      (86 vs <=80 un-swizzled) + attn split overhead -> reverted.
// R15: 256^2 4-phase counted-vmcnt GEMM REGRESSED (98us, MfmaUtil 20,
//      VALU 11, occ 12%): grids of 192/128 blocks can't fill 256 CUs and
//      1 blk/CU makes every barrier straggler global. 256^2 closed for
//      these shapes.
// R16: restore best-measured config (R3 = 302.4us: prep v1 + plain 128^2
//      gemm + R10 attn[+s_nop guards]) + XCD m-banding in gemm dispatch:
//      XCD x (fid%8) owns m-tile band [x*Bm,(x+1)*Bm), sweeps n. Per k-step
//      an XCD touches A-band slab 64KB + B slabs ~384KB -> first toucher
//      misses, ~23 co-resident blocks L2-hit. Mechanism: the m97 per-tile
//      vmcnt(0) drain cost ~ load latency (L2 200cy vs HBM 900cy); banding
//      converts most staging loads to L2 hits. Bijective remap, zero
//      correctness risk.

typedef __attribute__((ext_vector_type(8))) short shortx8;
typedef __attribute__((ext_vector_type(4))) float floatx4;

#define SEQ 2048
#define QSC 0.1803368801111204f   // (1/8) * log2(e), folded into Wq/bq

#if __has_builtin(__builtin_amdgcn_exp2f)
#define EXP2F(x) __builtin_amdgcn_exp2f(x)
#else
#define EXP2F(x) __expf((x) * 0.6931471805599453f)
#endif

__device__ __forceinline__ unsigned short f2bf(float f) {      // RNE
  union { float f; unsigned u; } a; a.f = f;
  unsigned u = a.u;
  u += 0x7fffu + ((u >> 16) & 1u);
  return (unsigned short)(u >> 16);
}

// packed f32x2 -> bf16x2 (RNE), single instruction
__device__ __forceinline__ unsigned cvtpkbf(float lo, float hi) {
  unsigned r;
  asm("v_cvt_pk_bf16_f32 %0, %1, %2" : "=v"(r) : "v"(lo), "v"(hi));
  return r;
}

// v_permlane32_swap_b32: a = {a_lo32, b_lo32}, b = {a_hi32, b_hi32}
// s_nop guard: permlane cross-lane reads need producer wait states; the
// compiler's hazard recognizer can't see inside inline asm, so guard here.
__device__ __forceinline__ void plswap(unsigned &a, unsigned &b) {
  asm("s_nop 1\n\tv_permlane32_swap_b32 %0, %1" : "+v"(a), "+v"(b));
}
// v_permlane16_swap_b32: within each 32-half, a = {a_lo16, b_lo16}, b = {a_hi16, b_hi16}
__device__ __forceinline__ void pl16swap(unsigned &a, unsigned &b) {
  asm("s_nop 1\n\tv_permlane16_swap_b32 %0, %1" : "+v"(a), "+v"(b));
}

// async global->LDS, 16B per lane; LDS dst = uniform base + lane*16
__device__ __forceinline__ void gload16(const unsigned short* g, unsigned short* l) {
  __builtin_amdgcn_global_load_lds((const __attribute__((address_space(1))) void*)g,
                                   (__attribute__((address_space(3))) void*)l, 16, 0, 0);
}

// ---------------- prep: cast x, transpose+cast all weights, concat bias ----------
// grid (64,64,6), block (32,8). z: 0=Wq(*QSC) 1=Wk 2=Wv 3=Wo 4=cast-x 5=bias.
__global__ void prep_kernel(const float* __restrict__ x,
                            const float* __restrict__ Wq, const float* __restrict__ Wk,
                            const float* __restrict__ Wv, const float* __restrict__ Wo,
                            const float* __restrict__ bq, const float* __restrict__ bk,
                            const float* __restrict__ bv,
                            unsigned short* __restrict__ WT,
                            unsigned short* __restrict__ WoT,
                            unsigned short* __restrict__ xb,
                            float* __restrict__ bqkv) {
  const int z = blockIdx.z;
  if (z == 4) {                       // cast x -> bf16, 2048 floats per block
    int fb = blockIdx.y * 64 + blockIdx.x;
    int tid = threadIdx.y * 32 + threadIdx.x;
    int i = fb * 2048 + tid * 8;
    float4 v0 = *(const float4*)(x + i);
    float4 v1 = *(const float4*)(x + i + 4);
    ushort4 o0, o1;
    o0.x = f2bf(v0.x); o0.y = f2bf(v0.y); o0.z = f2bf(v0.z); o0.w = f2bf(v0.w);
    o1.x = f2bf(v1.x); o1.y = f2bf(v1.y); o1.z = f2bf(v1.z); o1.w = f2bf(v1.w);
    *(ushort4*)(xb + i) = o0;
    *(ushort4*)(xb + i + 4) = o1;
    return;
  }
  if (z == 5) {                       // concat bias
    int fb = blockIdx.y * 64 + blockIdx.x;
    if (fb >= 12) return;
    int i = fb * 256 + threadIdx.y * 32 + threadIdx.x;
    if (i < 2048) bqkv[i] = bq[i] * QSC;
    else if (i < 2560) bqkv[i] = bk[i - 2048];
    else if (i < 3072) bqkv[i] = bv[i - 2560];
    return;
  }
  const float* W; unsigned short* D; int N; float sc = 1.f;
  if (z == 0)      { W = Wq; D = WT;               N = 2048; sc = QSC; }
  else if (z == 1) { W = Wk; D = WT + 2048 * 2048; N = 512; }
  else if (z == 2) { W = Wv; D = WT + 2560 * 2048; N = 512; }
  else             { W = Wo; D = WoT;              N = 2048; }
  if (blockIdx.x * 32 >= N) return;

  __shared__ float tile[32][33];
  int xx = blockIdx.x * 32 + threadIdx.x;
  int y0 = blockIdx.y * 32;
  for (int i = 0; i < 32; i += 8)
    tile[threadIdx.y + i][threadIdx.x] = W[(size_t)(y0 + threadIdx.y + i) * N + xx];
  __syncthreads();
  int nx = y0 + threadIdx.x;
  int ny = blockIdx.x * 32 + threadIdx.y;
  for (int i = 0; i < 32; i += 8)
    D[(size_t)(ny + i) * 2048 + nx] = f2bf(tile[threadIdx.x][threadIdx.y + i] * sc);
}

// ---------------- bf16 GEMM (m97 structure): C = A @ BT^T + bias ----------------
// 128x128 tile, BK=64, 4 waves (2x2), global_load_lds staging, swizzled LDS.
// MODE 0: fp32 out. MODE 2: QKV split (Q -> Cout bf16, K -> Kbuf, V -> Vt[gb][d][s]).
// R16: XCD m-band dispatch remap. XCD = fid%8 owns m-tiles [xcd*Bm, +Bm),
// sweeps n slowest. Bm = gridDim.x/8 (gridDim.x = 32 at both call sites).
template <int MODE>
__global__ __launch_bounds__(256) void gemm_bt(const unsigned short* __restrict__ A,
                                               const unsigned short* __restrict__ BT,
                                               const float* __restrict__ bias,
                                               void* __restrict__ Cout,
                                               unsigned short* __restrict__ Kbuf,
                                               unsigned short* __restrict__ Vt,
                                               int M, int N, int K) {
  __shared__ __align__(16) unsigned short As[128 * 64];
  __shared__ __align__(16) unsigned short Bs[128 * 64];
  const int fid = blockIdx.y * gridDim.x + blockIdx.x;
  const int Bm = gridDim.x >> 3;                 // m-tiles per XCD band
  const int xcd = fid & 7;
  const int jj = fid >> 3;                       // index within XCD
  const int m0 = (xcd * Bm + (jj % Bm)) * 128;
  const int n0 = (jj / Bm) * 128;
  const int tid = threadIdx.x;
  const int lane = tid & 63, wave = tid >> 6;
  const int l15 = lane & 15, quad = lane >> 4;
  const int wm = (wave & 1) * 64, wn = (wave >> 1) * 64;

  const int r8 = lane >> 3;
  const int clog = (lane & 7) ^ r8;
  const unsigned short* aSrc = A + (size_t)(m0 + wave * 32 + r8) * K + clog * 8;
  const unsigned short* bSrc = BT + (size_t)(n0 + wave * 32 + r8) * K + clog * 8;
  unsigned short* aDst = &As[wave * 2048];
  unsigned short* bDst = &Bs[wave * 2048];

  const int s = l15 & 7;
  int aoff[4], boff[4];
#pragma unroll
  for (int i = 0; i < 4; i++) aoff[i] = (wm + i * 16 + l15) * 64 + (quad ^ s) * 8;
#pragma unroll
  for (int j = 0; j < 4; j++) boff[j] = (wn + j * 16 + l15) * 64 + (quad ^ s) * 8;

  floatx4 acc[4][4];
#pragma unroll
  for (int i = 0; i < 4; i++)
#pragma unroll
    for (int j = 0; j < 4; j++)
#pragma unroll
      for (int r = 0; r < 4; r++) acc[i][j][r] = 0.f;

  for (int k0 = 0; k0 < K; k0 += 64) {
    __syncthreads();
#pragma unroll
    for (int j = 0; j < 4; j++) {
      gload16(aSrc + (size_t)j * 8 * K + k0, aDst + j * 512);
      gload16(bSrc + (size_t)j * 8 * K + k0, bDst + j * 512);
    }
    __syncthreads();
    {
      shortx8 af[4], bf[4];
#pragma unroll
      for (int i = 0; i < 4; i++) af[i] = *(const shortx8*)&As[aoff[i]];
#pragma unroll
      for (int j = 0; j < 4; j++) bf[j] = *(const shortx8*)&Bs[boff[j]];
#pragma unroll
      for (int i = 0; i < 4; i++)
#pragma unroll
        for (int j = 0; j < 4; j++)
          acc[i][j] = __builtin_amdgcn_mfma_f32_16x16x32_bf16(af[i], bf[j], acc[i][j], 0, 0, 0);
#pragma unroll
      for (int i = 0; i < 4; i++) af[i] = *(const shortx8*)&As[aoff[i] ^ 32];
#pragma unroll
      for (int j = 0; j < 4; j++) bf[j] = *(const shortx8*)&Bs[boff[j] ^ 32];
#pragma unroll
      for (int i = 0; i < 4; i++)
#pragma unroll
        for (int j = 0; j < 4; j++)
          acc[i][j] = __builtin_amdgcn_mfma_f32_16x16x32_bf16(af[i], bf[j], acc[i][j], 0, 0, 0);
    }
  }

#pragma unroll
  for (int i = 0; i < 4; i++) {
#pragma unroll
    for (int j = 0; j < 4; j++) {
      int col = n0 + wn + j * 16 + l15;
      float bv = bias[col];
#pragma unroll
      for (int r = 0; r < 4; r++) {
        int row = m0 + wm + i * 16 + quad * 4 + r;
        float v = acc[i][j][r] + bv;
        if (MODE == 0) {
          ((float*)Cout)[(size_t)row * N + col] = v;
        } else {
          if (col < 2048) {
            ((unsigned short*)Cout)[(size_t)row * 2048 + col] = f2bf(v);
          } else if (col < 2560) {
            Kbuf[(size_t)row * 512 + (col - 2048)] = f2bf(v);
          } else {
            int g = (col - 2560) >> 6, d = (col - 2560) & 63;
            int b = row >> 11, sidx = row & 2047;
            Vt[(size_t)(((g << 1) | b) * 64 + d) * 2048 + sidx] = f2bf(v);
          }
        }
      }
    }
  }
}

// ---------------- flash attention (group-shared K/V, dbuf, in-register P) --------
// grid (S/32=64, G=8, B=2); wave w = head g*4+w. Each wave: 32 q rows as 2
// q-sets of 16. K/V dbuf (1 barrier/tile). P stays in registers: QK C-frag is
// redistributed to PV B-frag via permlane32_swap then permlane16_swap (pure
// VALU butterfly, zero selects / LDS ops). LDS 32 KB -> 5 blocks/CU cap.
__global__ __launch_bounds__(256, 4) void attn_kernel(const unsigned short* __restrict__ Qb,
                                                      const unsigned short* __restrict__ Kb,
                                                      const unsigned short* __restrict__ Vt,
                                                      unsigned short* __restrict__ O) {
  const int qt = blockIdx.x, g = blockIdx.y, b = blockIdx.z;
  const int tid = threadIdx.x;
  const int lane = tid & 63, wave = tid >> 6;
  const int h = g * 4 + wave;
  const int l15 = lane & 15, quad = lane >> 4;

  __shared__ __align__(16) unsigned short Ks[2][64 * 64];  // [t][d] swizzled, 2x8 KB
  __shared__ __align__(16) unsigned short Vs[2][64 * 64];  // [d][t] swizzled, 2x8 KB

  // Q fragments for 2 q-sets (32 q rows per wave)
  shortx8 qf[2][2];
  {
    const unsigned short* qp = Qb + (size_t)(b * SEQ + qt * 32 + l15) * 2048 + h * 64 + quad * 8;
#pragma unroll
    for (int a = 0; a < 2; a++) {
      qf[a][0] = *(const shortx8*)(qp + (size_t)a * 16 * 2048);
      qf[a][1] = *(const shortx8*)(qp + (size_t)a * 16 * 2048 + 32);
    }
  }

  // staging: wave stages rows wave*16..+15 of each tile (2 issues of 8 rows)
  const int r8 = lane >> 3;
  const int clog = (lane & 7) ^ r8;
  const unsigned short* kSrc = Kb + ((size_t)b * SEQ + wave * 16 + r8) * 512 + g * 64 + clog * 8;
  const unsigned short* vSrc = Vt + ((size_t)((g * 2 + b) * 64 + wave * 16 + r8)) * 2048 + clog * 8;

  const int s = l15 & 7;
  int foff[4];
#pragma unroll
  for (int i = 0; i < 4; i++) foff[i] = (i * 16 + l15) * 64 + ((quad ^ s) * 8);

  shortx8 ones;
#pragma unroll
  for (int j = 0; j < 8; j++) ones[j] = (short)0x3F80;     // bf16 1.0

  floatx4 oacc[2][4], lacc[2];
#pragma unroll
  for (int a = 0; a < 2; a++) {
#pragma unroll
    for (int r = 0; r < 4; r++) lacc[a][r] = 0.f;
#pragma unroll
    for (int nd = 0; nd < 4; nd++)
#pragma unroll
      for (int r = 0; r < 4; r++) oacc[a][nd][r] = 0.f;
  }

  // prologue: stage tile 0 into buffer 0
  {
    unsigned short* kD = &Ks[0][wave * 1024];
    unsigned short* vD = &Vs[0][wave * 1024];
    gload16(kSrc, kD);
    gload16(kSrc + (size_t)8 * 512, kD + 512);
    gload16(vSrc, vD);
    gload16(vSrc + (size_t)8 * 2048, vD + 512);
  }
  __syncthreads();

  for (int it = 0; it < SEQ / 64; it++) {
    const int p = it & 1;
    // prefetch next tile into the other buffer (async; drained by the
    // end-of-iter barrier, ~1 tile of compute later)
    if (it < SEQ / 64 - 1) {
      const size_t t1 = (size_t)(it + 1) * 64;
      unsigned short* kD = &Ks[p ^ 1][wave * 1024];
      unsigned short* vD = &Vs[p ^ 1][wave * 1024];
      gload16(kSrc + t1 * 512, kD);
      gload16(kSrc + (t1 + 8) * 512, kD + 512);
      gload16(vSrc + t1, vD);
      gload16(vSrc + (size_t)8 * 2048 + t1, vD + 512);
    }

    // K fragments (reused by both q-sets)
    shortx8 kf[4][2];
#pragma unroll
    for (int i = 0; i < 4; i++) {
      kf[i][0] = *(const shortx8*)&Ks[p][foff[i]];
      kf[i][1] = *(const shortx8*)&Ks[p][foff[i] ^ 32];
    }

    // phase 1: per q-set QK^T -> exp -> pure-VALU butterfly -> PV B-frags.
    // sc[i][r] = score[t = i*16 + quad*4 + r][q = l15]. Pack pairs (cvt_pk):
    // E[i][c] = pair(t = 16i + 4quad + 2c). Target: pfr[a][ks].u32[m] =
    // pair(t = 32ks + 8quad + 2m): element W[i][c]@(b4,b5) lands at
    // lane(b4'=b5, b5'=i&1), slot m=2*b4+c, ks=i>>1 via plswap then pl16swap.
    shortx8 pfr[2][2];
#pragma unroll
    for (int a = 0; a < 2; a++) {
      floatx4 sc[4];
      __builtin_amdgcn_s_setprio(1);
#pragma unroll
      for (int i = 0; i < 4; i++) {
        floatx4 c = {0.f, 0.f, 0.f, 0.f};
        c = __builtin_amdgcn_mfma_f32_16x16x32_bf16(kf[i][0], qf[a][0], c, 0, 0, 0);
        c = __builtin_amdgcn_mfma_f32_16x16x32_bf16(kf[i][1], qf[a][1], c, 0, 0, 0);
        sc[i] = c;
      }
      __builtin_amdgcn_s_setprio(0);
      unsigned E00 = cvtpkbf(EXP2F(sc[0][0]), EXP2F(sc[0][1]));
      unsigned E01 = cvtpkbf(EXP2F(sc[0][2]), EXP2F(sc[0][3]));
      unsigned E10 = cvtpkbf(EXP2F(sc[1][0]), EXP2F(sc[1][1]));
      unsigned E11 = cvtpkbf(EXP2F(sc[1][2]), EXP2F(sc[1][3]));
      unsigned E20 = cvtpkbf(EXP2F(sc[2][0]), EXP2F(sc[2][1]));
      unsigned E21 = cvtpkbf(EXP2F(sc[2][2]), EXP2F(sc[2][3]));
      unsigned E30 = cvtpkbf(EXP2F(sc[3][0]), EXP2F(sc[3][1]));
      unsigned E31 = cvtpkbf(EXP2F(sc[3][2]), EXP2F(sc[3][3]));
      // stage A: lane^32 routing (b5' = i&1)
      plswap(E00, E10); plswap(E01, E11);   // ks=0
      plswap(E20, E30); plswap(E21, E31);   // ks=1
      // stage B: lane^16 routing (src b4 = m>>1) — no selects needed
      pl16swap(E00, E10); pl16swap(E01, E11);
      pl16swap(E20, E30); pl16swap(E21, E31);
      union { unsigned u[4]; shortx8 v; } P0, P1;
      P0.u[0] = E00; P0.u[1] = E01; P0.u[2] = E10; P0.u[3] = E11;
      P1.u[0] = E20; P1.u[1] = E21; P1.u[2] = E30; P1.u[3] = E31;
      pfr[a][0] = P0.v;
      pfr[a][1] = P1.v;
    }

    // phase 2: V fragments, then PV + l row-sum for both q-sets (MFMA burst)
    shortx8 vf[4][2];
#pragma unroll
    for (int nd = 0; nd < 4; nd++) {
      vf[nd][0] = *(const shortx8*)&Vs[p][foff[nd]];
      vf[nd][1] = *(const shortx8*)&Vs[p][foff[nd] ^ 32];
    }
#pragma unroll
    for (int a = 0; a < 2; a++) {
#pragma unroll
      for (int ks = 0; ks < 2; ks++) {
        shortx8 pf = pfr[a][ks];
        __builtin_amdgcn_s_setprio(1);
#pragma unroll
        for (int nd = 0; nd < 4; nd++)
          oacc[a][nd] = __builtin_amdgcn_mfma_f32_16x16x32_bf16(vf[nd][ks], pf, oacc[a][nd], 0, 0, 0);
        lacc[a] = __builtin_amdgcn_mfma_f32_16x16x32_bf16(ones, pf, lacc[a], 0, 0, 0);
        __builtin_amdgcn_s_setprio(0);
      }
    }
    __syncthreads();   // buffer p free; prefetch into p^1 drained
  }

  // epilogue: lacc rows identical -> l = lacc[a][0]; O^T cols q, rows d contiguous
#pragma unroll
  for (int a = 0; a < 2; a++) {
    float inv = 1.f / lacc[a][0];
    unsigned short* oPtr = O + (size_t)(b * SEQ + qt * 32 + a * 16 + l15) * 2048 + h * 64 + quad * 4;
#pragma unroll
    for (int nd = 0; nd < 4; nd++) {
      uint2 w;
      w.x = (unsigned)f2bf(oacc[a][nd][0] * inv) | ((unsigned)f2bf(oacc[a][nd][1] * inv) << 16);
      w.y = (unsigned)f2bf(oacc[a][nd][2] * inv) | ((unsigned)f2bf(oacc[a][nd][3] * inv) << 16);
      *(uint2*)(oPtr + nd * 16) = w;
    }
  }
}

extern "C" void kernel_launch(void* const* d_in, const int* in_sizes, int n_in,
                              void* d_out, int out_size, void* d_ws, size_t ws_size,
                              hipStream_t stream) {
  const float* x  = (const float*)d_in[0];
  const float* Wq = (const float*)d_in[1];
  const float* bq = (const float*)d_in[2];
  const float* Wk = (const float*)d_in[3];
  const float* bk = (const float*)d_in[4];
  const float* Wv = (const float*)d_in[5];
  const float* bv = (const float*)d_in[6];
  const float* Wo = (const float*)d_in[7];
  const float* bo = (const float*)d_in[8];
  float* out = (float*)d_out;

  // workspace layout (62,930,944 B total)
  char* ws = (char*)d_ws;
  unsigned short* WTall = (unsigned short*)ws;                          // [3072][2048] 12,582,912
  unsigned short* WoT   = (unsigned short*)(ws + 12582912);             // [2048][2048]  8,388,608
  float*          bqkv  = (float*)(ws + 20971520);                      // [3072] + pad      16384
  unsigned short* xb    = (unsigned short*)(ws + 20987904);             // [4096][2048] 16,777,216
  unsigned short* Qbuf  = (unsigned short*)(ws + 37765120);             // [4096][2048] 16,777,216
  unsigned short* Kbuf  = (unsigned short*)(ws + 54542336);             // [4096][512]   4,194,304
  unsigned short* Vt    = (unsigned short*)(ws + 58736640);             // [16][64][2048] 4,194,304
  unsigned short* Og    = xb;  // attention output reuses xb

  // 1. prep: cast x, transpose+cast weights (Wq pre-scaled), concat bias
  prep_kernel<<<dim3(64, 64, 6), dim3(32, 8), 0, stream>>>(
      x, Wq, Wk, Wv, Wo, bq, bk, bv, WTall, WoT, xb, bqkv);

  // 2. QKV projection: Q -> Qbuf, K -> Kbuf, V -> Vt (transposed)
  gemm_bt<2><<<dim3(32, 24), 256, 0, stream>>>(xb, WTall, bqkv, Qbuf, Kbuf, Vt, 4096, 3072, 2048);

  // 3. grouped flash attention -> Og [4096][2048] bf16
  attn_kernel<<<dim3(64, 8, 2), 256, 0, stream>>>(Qbuf, Kbuf, Vt, Og);

  // 4. output projection -> fp32 out
  gemm_bt<0><<<dim3(32, 16), 256, 0, stream>>>(Og, WoT, bo, out, nullptr, nullptr, 4096, 2048, 2048);
}